// Round 1
// baseline (475.221 us; speedup 1.0000x reference)
//
#include <hip/hip_runtime.h>

// MDTA: B=4, C=384, H=W=128, HEADS=8, D=48
#define HW    16384
#define WD    128
#define CCH   384
#define NB    4
#define NHEAD 8
#define DH    48

typedef unsigned short u16;
typedef unsigned int   u32;
typedef __bf16 bf16x8 __attribute__((ext_vector_type(8)));
typedef float  f32x4  __attribute__((ext_vector_type(4)));

__device__ __forceinline__ float bf2f(u16 u){ u32 t=((u32)u)<<16; float f; __builtin_memcpy(&f,&t,4); return f; }
__device__ __forceinline__ u16 f2bf(float f){ u32 x; __builtin_memcpy(&x,&f,4); u32 r=x+0x7fffu+((x>>16)&1u); return (u16)(r>>16); }
__device__ __forceinline__ f32x4 zero4(){ f32x4 z = {0.f,0.f,0.f,0.f}; return z; }

#define GL16(g,l) __builtin_amdgcn_global_load_lds(\
    (const __attribute__((address_space(1))) void*)(g), \
    (__attribute__((address_space(3))) void*)(l), 16, 0, 0)

// ---------------- prep: cast/concat weights ----------------
__global__ void prep_kernel(const float* wq_p, const float* wk_p, const float* wv_p,
                            const float* bq_p, const float* bk_p, const float* bv_p,
                            const float* wq_d, const float* wk_d, const float* wv_d,
                            const float* bq_d, const float* bk_d, const float* bv_d,
                            u16* Wqkv, float* bias_p, float* wdc, float* bdc)
{
    int idx = blockIdx.x*256 + threadIdx.x;
    const int NW = 3*CCH*CCH;                 // 442368
    if (idx < NW) {
        int m = idx / CCH, c = idx % CCH;
        int w = m / CCH, o = m % CCH;
        const float* src = (w==0)? wq_p : (w==1)? wk_p : wv_p;
        Wqkv[idx] = f2bf(src[o*CCH + c]);
    } else if (idx < NW + 3*CCH) {
        int m = idx - NW; int w = m/CCH, o = m%CCH;
        const float* src = (w==0)? bq_p : (w==1)? bk_p : bv_p;
        bias_p[m] = src[o];
    } else if (idx < NW + 3*CCH + 3*CCH*9) {
        int r = idx - NW - 3*CCH; int m = r/9, k = r%9;
        int w = m/CCH, o = m%CCH;
        const float* src = (w==0)? wq_d : (w==1)? wk_d : wv_d;
        wdc[r] = src[o*9 + k];
    } else if (idx < NW + 3*CCH + 3*CCH*9 + 3*CCH) {
        int m = idx - NW - 3*CCH - 3*CCH*9; int w = m/CCH, o = m%CCH;
        const float* src = (w==0)? bq_d : (w==1)? bk_d : bv_d;
        bdc[m] = src[o];
    }
}

// ---------------- LayerNorm over C per pixel -> xn bf16 [b][c][p] ----------------
__global__ void ln_kernel(const float* __restrict__ x, const float* __restrict__ gamma,
                          const float* __restrict__ beta, u16* __restrict__ xn)
{
    __shared__ float ps[4][64], ps2[4][64];
    int b  = blockIdx.y;
    int p0 = blockIdx.x*64;
    int t  = threadIdx.x;
    int pg = t >> 6, px = t & 63;             // wave pg handles channels [pg*96, +96)
    const float* xb = x + (size_t)b*CCH*HW + p0 + px;
    float s = 0.f, s2 = 0.f;
    int cbase = pg*96;
    for (int cc = 0; cc < 96; ++cc) {
        float v = xb[(size_t)(cbase+cc)*HW];
        s += v; s2 += v*v;
    }
    ps[pg][px] = s; ps2[pg][px] = s2;
    __syncthreads();
    float st  = ps[0][px]+ps[1][px]+ps[2][px]+ps[3][px];
    float st2 = ps2[0][px]+ps2[1][px]+ps2[2][px]+ps2[3][px];
    float mu  = st*(1.f/CCH);
    float var = st2*(1.f/CCH) - mu*mu;
    float rs  = rsqrtf(var + 1e-5f);
    u16* xo = xn + (size_t)b*CCH*HW + p0 + px;
    for (int cc = 0; cc < 96; ++cc) {
        int c = cbase + cc;
        float v = xb[(size_t)c*HW];
        xo[(size_t)c*HW] = f2bf((v-mu)*rs*gamma[c] + beta[c]);
    }
}

// ---------------- bf16 transpose per batch: [384][16384] -> [16384][384] ----------------
__global__ void transpose_kernel(const u16* __restrict__ src, u16* __restrict__ dst)
{
    __shared__ u32 tile[64][33];              // u32 = 2 bf16 along p
    int b  = blockIdx.z;
    int p0 = blockIdx.x*64, c0 = blockIdx.y*64;
    const u16* s = src + (size_t)b*CCH*HW;
    u16*       d = dst + (size_t)b*CCH*HW;
    int t = threadIdx.x;
    #pragma unroll
    for (int q = 0; q < 2; ++q) {
        int cc = q*32 + (t>>3), pg = t&7;
        uint4 v = *(const uint4*)(s + (size_t)(c0+cc)*HW + p0 + pg*8);
        tile[cc][pg*4+0] = v.x; tile[cc][pg*4+1] = v.y;
        tile[cc][pg*4+2] = v.z; tile[cc][pg*4+3] = v.w;
    }
    __syncthreads();
    #pragma unroll
    for (int q = 0; q < 2; ++q) {
        int pp = q*32 + (t>>3), cg = t&7;
        u32 outw[4];
        #pragma unroll
        for (int jj = 0; jj < 4; ++jj) {
            int c_a = cg*8 + jj*2;
            u32 wa = tile[c_a  ][pp>>1];
            u32 wb = tile[c_a+1][pp>>1];
            u16 ua = (pp&1) ? (u16)(wa>>16) : (u16)wa;
            u16 ub = (pp&1) ? (u16)(wb>>16) : (u16)wb;
            outw[jj] = (u32)ua | ((u32)ub<<16);
        }
        *(uint4*)(d + (size_t)(p0+pp)*CCH + c0 + cg*8) = make_uint4(outw[0],outw[1],outw[2],outw[3]);
    }
}

// ---------------- NT MFMA GEMM: C[m][n] = sum_k A[m][k]*B[n][k]  (ld=384, K=384) ----------------
// 128x128 tile, BK=64, 4 waves (each 64x64 = 4x4 frags of 16x16), global_load_lds staging,
// XOR-swizzled LDS (linear dest + pre-swizzled source + swizzled read).
// EPI 0: +bias, store bf16 (row-stride HW). EPI 1: +bias +xn(bf16), store f32.
template<int EPI>
__global__ __launch_bounds__(256) void gemm_nt(
    const u16* __restrict__ A, const u16* __restrict__ Bm, void* __restrict__ Cout,
    const float* __restrict__ bias, const u16* __restrict__ xnadd,
    long A_bstride, long B_bstride, long C_bstride)
{
    __shared__ u16 smA[128*64];
    __shared__ u16 smB[128*64];
    int b  = blockIdx.z;
    int n0 = blockIdx.x*128, m0 = blockIdx.y*128;
    const u16* Ab = A  + (size_t)b*A_bstride;
    const u16* Bb = Bm + (size_t)b*B_bstride;
    int t = threadIdx.x;
    int lane = t & 63, w = t >> 6;
    int wr = w >> 1, wc = w & 1;
    int l15 = lane & 15, g = lane >> 4;
    int s7 = l15 & 7;

    f32x4 acc[4][4];
    #pragma unroll
    for (int i=0;i<4;++i)
        #pragma unroll
        for (int j=0;j<4;++j) acc[i][j] = zero4();

    for (int ks = 0; ks < 6; ++ks) {
        int k0 = ks*64;
        #pragma unroll
        for (int r = 0; r < 4; ++r) {
            int e   = (r*256 + t)*8;
            int row = e >> 6, kk = e & 63;
            int kks = kk ^ ((row&7)<<3);      // pre-swizzle source so linear LDS dest is swizzled
            GL16(Ab + (size_t)(m0+row)*CCH + k0 + kks, smA + r*2048 + w*512);
            GL16(Bb + (size_t)(n0+row)*CCH + k0 + kks, smB + r*2048 + w*512);
        }
        __syncthreads();
        #pragma unroll
        for (int kh = 0; kh < 2; ++kh) {
            bf16x8 af[4], bq[4];
            #pragma unroll
            for (int mi=0;mi<4;++mi) {
                int row = wr*64 + mi*16 + l15;
                int u = (kh*4 + g) ^ s7;
                af[mi] = *(const bf16x8*)&smA[row*64 + u*8];
            }
            #pragma unroll
            for (int nj=0;nj<4;++nj) {
                int row = wc*64 + nj*16 + l15;
                int u = (kh*4 + g) ^ s7;
                bq[nj] = *(const bf16x8*)&smB[row*64 + u*8];
            }
            #pragma unroll
            for (int mi=0;mi<4;++mi)
                #pragma unroll
                for (int nj=0;nj<4;++nj)
                    acc[mi][nj] = __builtin_amdgcn_mfma_f32_16x16x32_bf16(af[mi], bq[nj], acc[mi][nj], 0,0,0);
        }
        __syncthreads();
    }
    #pragma unroll
    for (int mi=0;mi<4;++mi) {
        #pragma unroll
        for (int r=0;r<4;++r) {
            int grow = m0 + wr*64 + mi*16 + g*4 + r;
            float bv = bias[grow];
            #pragma unroll
            for (int nj=0;nj<4;++nj) {
                int gcol = n0 + wc*64 + nj*16 + l15;
                float v = acc[mi][nj][r] + bv;
                if (EPI == 0) {
                    ((u16*)Cout)[(size_t)b*C_bstride + (size_t)grow*HW + gcol] = f2bf(v);
                } else {
                    v += bf2f(xnadd[(size_t)b*CCH*HW + (size_t)grow*HW + gcol]);
                    ((float*)Cout)[(size_t)b*C_bstride + (size_t)grow*HW + gcol] = v;
                }
            }
        }
    }
}

// ---------------- depthwise 3x3 SAME, bf16 in/out, [b][c][p] ----------------
__global__ void dw_kernel(const u16* __restrict__ in, u16* __restrict__ out,
                          const float* __restrict__ wd, const float* __restrict__ bd)
{
    int b  = blockIdx.z;
    int c  = blockIdx.y;
    int yt = blockIdx.x;
    int t  = threadIdx.x;
    int ty = t >> 4, tx = t & 15;
    int y  = yt*16 + ty;
    int x0 = tx*8;
    const u16* ib = in + (size_t)b*CCH*HW + (size_t)c*HW;
    float w9[9];
    #pragma unroll
    for (int i=0;i<9;++i) w9[i] = wd[c*9+i];
    float bv = bd[c];
    float rows[3][10];
    #pragma unroll
    for (int dy=0; dy<3; ++dy) {
        int yy = y + dy - 1;
        if (yy < 0 || yy >= WD) { for (int i=0;i<10;++i) rows[dy][i]=0.f; continue; }
        const u16* rp = ib + yy*WD;
        rows[dy][0] = (x0==0) ? 0.f : bf2f(rp[x0-1]);
        uint4 v = *(const uint4*)(rp + x0);
        u16 e[8]; __builtin_memcpy(e,&v,16);
        #pragma unroll
        for (int i=0;i<8;++i) rows[dy][1+i] = bf2f(e[i]);
        rows[dy][9] = (x0+8 >= WD) ? 0.f : bf2f(rp[x0+8]);
    }
    u16 ovals[8];
    #pragma unroll
    for (int xo=0; xo<8; ++xo) {
        float a = bv;
        #pragma unroll
        for (int dy=0;dy<3;++dy)
            #pragma unroll
            for (int dx=0;dx<3;++dx)
                a += rows[dy][xo+dx] * w9[dy*3+dx];
        ovals[xo] = f2bf(a);
    }
    uint4 ov; __builtin_memcpy(&ov, ovals, 16);
    *(uint4*)(out + (size_t)b*CCH*HW + (size_t)c*HW + y*WD + x0) = ov;
}

// ---------------- scores partials: S[i][j] += sum_p K[i,p]*Q[j,p] over a 512-pixel chunk ----------------
__global__ void scores_kernel(const u16* __restrict__ dwK, const u16* __restrict__ dwQ,
                              float* __restrict__ S_part)
{
    int pc = blockIdx.x;                      // 0..31 pixel chunks of 512
    int h  = blockIdx.y;
    int b  = blockIdx.z;
    int lane = threadIdx.x;                   // 64
    int l15 = lane & 15, g = lane >> 4;
    const u16* Kb = dwK + (size_t)b*CCH*HW + (size_t)(h*DH)*HW;
    const u16* Qb = dwQ + (size_t)b*CCH*HW + (size_t)(h*DH)*HW;
    int p0 = pc*512;
    f32x4 acc[3][3];
    #pragma unroll
    for (int i=0;i<3;++i)
        #pragma unroll
        for (int j=0;j<3;++j) acc[i][j] = zero4();
    for (int kk=0; kk<16; ++kk) {
        int p = p0 + kk*32 + g*8;
        bf16x8 af[3], bq[3];
        #pragma unroll
        for (int it=0; it<3; ++it)
            af[it] = *(const bf16x8*)(Kb + (size_t)(it*16 + l15)*HW + p);
        #pragma unroll
        for (int jt=0; jt<3; ++jt)
            bq[jt] = *(const bf16x8*)(Qb + (size_t)(jt*16 + l15)*HW + p);
        #pragma unroll
        for (int it=0;it<3;++it)
            #pragma unroll
            for (int jt=0;jt<3;++jt)
                acc[it][jt] = __builtin_amdgcn_mfma_f32_16x16x32_bf16(af[it], bq[jt], acc[it][jt], 0,0,0);
    }
    float* Sp = S_part + ((size_t)pc*32 + b*NHEAD + h)*(DH*DH);
    #pragma unroll
    for (int it=0;it<3;++it)
        #pragma unroll
        for (int jt=0;jt<3;++jt)
            #pragma unroll
            for (int r=0;r<4;++r) {
                int i = it*16 + g*4 + r;
                int j = jt*16 + l15;
                Sp[i*DH + j] = acc[it][jt][r];
            }
}

// ---------------- reduce partials + softmax over j ----------------
__global__ void sm_kernel(const float* __restrict__ S_part, const float* __restrict__ alpha,
                          float* __restrict__ soft)
{
    __shared__ float S[DH*DH];
    int bh = blockIdx.x;                      // b*8+h
    int h  = bh & 7;
    int t  = threadIdx.x;                     // 64
    float ia = 1.f / alpha[h];
    for (int e = t; e < DH*DH; e += 64) {
        float s = 0.f;
        for (int pc=0; pc<32; ++pc) s += S_part[((size_t)pc*32 + bh)*(DH*DH) + e];
        S[e] = s * ia;
    }
    __syncthreads();
    if (t < DH) {
        float m = -1e30f;
        for (int j=0;j<DH;++j) m = fmaxf(m, S[t*DH+j]);
        float sum = 0.f;
        for (int j=0;j<DH;++j) sum += __expf(S[t*DH+j]-m);
        float inv = 1.f/sum;
        for (int j=0;j<DH;++j)
            soft[(size_t)bh*(DH*DH) + t*DH + j] = __expf(S[t*DH+j]-m)*inv;
    }
}

// ---------------- fold softmax into wf: wf_eff[b][o][n*48+i] = sum_j wf[o][n*48+j]*soft[b,n,i,j] ----------------
__global__ void fold_kernel(const float* __restrict__ wf, const float* __restrict__ soft,
                            u16* __restrict__ wf_eff)
{
    int idx = blockIdx.x*256 + threadIdx.x;
    if (idx >= NB*CCH*CCH) return;
    int b = idx / (CCH*CCH);
    int rem = idx % (CCH*CCH);
    int o = rem / CCH, c = rem % CCH;
    int n = c / DH, i = c % DH;
    const float* wrow = wf + (size_t)o*CCH + n*DH;
    const float* srow = soft + ((size_t)(b*NHEAD+n))*(DH*DH) + i*DH;
    float a = 0.f;
    #pragma unroll
    for (int j=0;j<DH;++j) a += wrow[j]*srow[j];
    wf_eff[idx] = f2bf(a);
}

extern "C" void kernel_launch(void* const* d_in, const int* in_sizes, int n_in,
                              void* d_out, int out_size, void* d_ws, size_t ws_size,
                              hipStream_t stream)
{
    const float* x    = (const float*)d_in[0];
    const float* ln_g = (const float*)d_in[1];
    const float* ln_b = (const float*)d_in[2];
    const float* wq_p = (const float*)d_in[3];
    const float* bq_p = (const float*)d_in[4];
    const float* wq_d = (const float*)d_in[5];
    const float* bq_d = (const float*)d_in[6];
    const float* wk_p = (const float*)d_in[7];
    const float* bk_p = (const float*)d_in[8];
    const float* wk_d = (const float*)d_in[9];
    const float* bk_d = (const float*)d_in[10];
    const float* wv_p = (const float*)d_in[11];
    const float* bv_p = (const float*)d_in[12];
    const float* wv_d = (const float*)d_in[13];
    const float* bv_d = (const float*)d_in[14];
    const float* alpha= (const float*)d_in[15];
    const float* wf   = (const float*)d_in[16];
    const float* bf_  = (const float*)d_in[17];

    char* ws = (char*)d_ws;
    size_t off = 0;
    auto alloc = [&](size_t bytes)->char* { char* p = ws + off; off += (bytes + 255) & ~(size_t)255; return p; };
    const size_t BIG = (size_t)NB*CCH*HW*2;   // 50.3 MB bf16 [b][384][16384]
    u16* xn_cp = (u16*)alloc(BIG);
    u16* xn_t  = (u16*)alloc(BIG);
    u16* pwA   = (u16*)alloc(BIG);
    u16* dwQ   = (u16*)alloc(BIG);
    u16* dwK   = (u16*)alloc(BIG);
    u16*   Wqkv   = (u16*)  alloc((size_t)3*CCH*CCH*2);
    float* bias_p = (float*)alloc((size_t)3*CCH*4);
    float* wdc    = (float*)alloc((size_t)3*CCH*9*4);
    float* bdc    = (float*)alloc((size_t)3*CCH*4);
    float* S_part = (float*)alloc((size_t)32*32*DH*DH*4);
    float* soft   = (float*)alloc((size_t)32*DH*DH*4);
    u16*   wf_eff = (u16*)  alloc((size_t)NB*CCH*CCH*2);
    if (off > ws_size) return;                // insufficient workspace -> leave poison (visible failure)
    u16* V_t = xn_t;                          // xn_t dead after last pointwise GEMM
    u16* dwV = dwQ;                           // dwQ dead after scores

    const long BStr = (long)CCH*HW;

    prep_kernel<<<1778, 256, 0, stream>>>(wq_p,wk_p,wv_p, bq_p,bk_p,bv_p,
                                          wq_d,wk_d,wv_d, bq_d,bk_d,bv_d,
                                          Wqkv, bias_p, wdc, bdc);
    ln_kernel<<<dim3(256,NB), 256, 0, stream>>>(x, ln_g, ln_b, xn_cp);
    transpose_kernel<<<dim3(256,6,NB), 256, 0, stream>>>(xn_cp, xn_t);

    // Q
    gemm_nt<0><<<dim3(128,3,NB), 256, 0, stream>>>(Wqkv,            xn_t, pwA, bias_p,        nullptr, 0, BStr, BStr);
    dw_kernel<<<dim3(8,CCH,NB), 256, 0, stream>>>(pwA, dwQ, wdc,          bdc);
    // K
    gemm_nt<0><<<dim3(128,3,NB), 256, 0, stream>>>(Wqkv + CCH*CCH,  xn_t, pwA, bias_p + CCH,  nullptr, 0, BStr, BStr);
    dw_kernel<<<dim3(8,CCH,NB), 256, 0, stream>>>(pwA, dwK, wdc + CCH*9,  bdc + CCH);
    // attention (tiny): scores -> softmax -> fold into wf
    scores_kernel<<<dim3(32,NHEAD,NB), 64, 0, stream>>>(dwK, dwQ, S_part);
    sm_kernel<<<32, 64, 0, stream>>>(S_part, alpha, soft);
    fold_kernel<<<2304, 256, 0, stream>>>(wf, soft, wf_eff);
    // V (reuses dwQ buffer; transpose into xn_t region)
    gemm_nt<0><<<dim3(128,3,NB), 256, 0, stream>>>(Wqkv + 2*CCH*CCH, xn_t, pwA, bias_p + 2*CCH, nullptr, 0, BStr, BStr);
    dw_kernel<<<dim3(8,CCH,NB), 256, 0, stream>>>(pwA, dwV, wdc + 2*CCH*9, bdc + 2*CCH);
    transpose_kernel<<<dim3(256,6,NB), 256, 0, stream>>>(dwV, V_t);
    // final: x_cap = wf_eff x V + bf + xn
    gemm_nt<1><<<dim3(128,3,NB), 256, 0, stream>>>(wf_eff, V_t, d_out, bf_, xn_cp,
                                                   (long)CCH*CCH, BStr, BStr);
}

// Round 2
// 402.794 us; speedup vs baseline: 1.1798x; 1.1798x over previous
//
#include <hip/hip_runtime.h>

// MDTA: B=4, C=384, H=W=128, HEADS=8, D=48
#define HW    16384
#define WD    128
#define CCH   384
#define NB    4
#define NHEAD 8
#define DH    48
#define NCHUNK 8   // score partial chunks (pixels per chunk = HW/NCHUNK = 2048)

typedef unsigned short u16;
typedef unsigned int   u32;
typedef __bf16 bf16x8 __attribute__((ext_vector_type(8)));
typedef float  f32x4  __attribute__((ext_vector_type(4)));

__device__ __forceinline__ float bf2f(u16 u){ u32 t=((u32)u)<<16; float f; __builtin_memcpy(&f,&t,4); return f; }
__device__ __forceinline__ u16 f2bf(float f){ u32 x; __builtin_memcpy(&x,&f,4); u32 r=x+0x7fffu+((x>>16)&1u); return (u16)(r>>16); }
__device__ __forceinline__ f32x4 zero4(){ f32x4 z = {0.f,0.f,0.f,0.f}; return z; }

#define GL16(g,l) __builtin_amdgcn_global_load_lds(\
    (const __attribute__((address_space(1))) void*)(g), \
    (__attribute__((address_space(3))) void*)(l), 16, 0, 0)

// ---------------- prep: cast/concat weights ----------------
__global__ void prep_kernel(const float* wq_p, const float* wk_p, const float* wv_p,
                            const float* bq_p, const float* bk_p, const float* bv_p,
                            const float* wq_d, const float* wk_d, const float* wv_d,
                            const float* bq_d, const float* bk_d, const float* bv_d,
                            u16* Wqkv, float* bias_p, float* wdc, float* bdc)
{
    int idx = blockIdx.x*256 + threadIdx.x;
    const int NW = 3*CCH*CCH;                 // 442368
    if (idx < NW) {
        int m = idx / CCH, c = idx % CCH;
        int w = m / CCH, o = m % CCH;
        const float* src = (w==0)? wq_p : (w==1)? wk_p : wv_p;
        Wqkv[idx] = f2bf(src[o*CCH + c]);
    } else if (idx < NW + 3*CCH) {
        int m = idx - NW; int w = m/CCH, o = m%CCH;
        const float* src = (w==0)? bq_p : (w==1)? bk_p : bv_p;
        bias_p[m] = src[o];
    } else if (idx < NW + 3*CCH + 3*CCH*9) {
        int r = idx - NW - 3*CCH; int m = r/9, k = r%9;
        int w = m/CCH, o = m%CCH;
        const float* src = (w==0)? wq_d : (w==1)? wk_d : wv_d;
        wdc[r] = src[o*9 + k];
    } else if (idx < NW + 3*CCH + 3*CCH*9 + 3*CCH) {
        int m = idx - NW - 3*CCH - 3*CCH*9; int w = m/CCH, o = m%CCH;
        const float* src = (w==0)? bq_d : (w==1)? bk_d : bv_d;
        bdc[m] = src[o];
    }
}

// ---------------- LayerNorm over C per pixel -> xn bf16 [b][c][p] ----------------
__global__ void ln_kernel(const float* __restrict__ x, const float* __restrict__ gamma,
                          const float* __restrict__ beta, u16* __restrict__ xn)
{
    __shared__ float ps[4][64], ps2[4][64];
    int b  = blockIdx.y;
    int p0 = blockIdx.x*64;
    int t  = threadIdx.x;
    int pg = t >> 6, px = t & 63;             // wave pg handles channels [pg*96, +96)
    const float* xb = x + (size_t)b*CCH*HW + p0 + px;
    float s = 0.f, s2 = 0.f;
    int cbase = pg*96;
    for (int cc = 0; cc < 96; ++cc) {
        float v = xb[(size_t)(cbase+cc)*HW];
        s += v; s2 += v*v;
    }
    ps[pg][px] = s; ps2[pg][px] = s2;
    __syncthreads();
    float st  = ps[0][px]+ps[1][px]+ps[2][px]+ps[3][px];
    float st2 = ps2[0][px]+ps2[1][px]+ps2[2][px]+ps2[3][px];
    float mu  = st*(1.f/CCH);
    float var = st2*(1.f/CCH) - mu*mu;
    float rs  = rsqrtf(var + 1e-5f);
    u16* xo = xn + (size_t)b*CCH*HW + p0 + px;
    for (int cc = 0; cc < 96; ++cc) {
        int c = cbase + cc;
        float v = xb[(size_t)c*HW];
        xo[(size_t)c*HW] = f2bf((v-mu)*rs*gamma[c] + beta[c]);
    }
}

// ---------------- bf16 transpose per batch: [384][16384] -> [16384][384] ----------------
__global__ void transpose_kernel(const u16* __restrict__ src, u16* __restrict__ dst)
{
    __shared__ u32 tile[64][33];              // u32 = 2 bf16 along p
    int b  = blockIdx.z;
    int p0 = blockIdx.x*64, c0 = blockIdx.y*64;
    const u16* s = src + (size_t)b*CCH*HW;
    u16*       d = dst + (size_t)b*CCH*HW;
    int t = threadIdx.x;
    #pragma unroll
    for (int q = 0; q < 2; ++q) {
        int cc = q*32 + (t>>3), pg = t&7;
        uint4 v = *(const uint4*)(s + (size_t)(c0+cc)*HW + p0 + pg*8);
        tile[cc][pg*4+0] = v.x; tile[cc][pg*4+1] = v.y;
        tile[cc][pg*4+2] = v.z; tile[cc][pg*4+3] = v.w;
    }
    __syncthreads();
    #pragma unroll
    for (int q = 0; q < 2; ++q) {
        int pp = q*32 + (t>>3), cg = t&7;
        u32 outw[4];
        #pragma unroll
        for (int jj = 0; jj < 4; ++jj) {
            int c_a = cg*8 + jj*2;
            u32 wa = tile[c_a  ][pp>>1];
            u32 wb = tile[c_a+1][pp>>1];
            u16 ua = (pp&1) ? (u16)(wa>>16) : (u16)wa;
            u16 ub = (pp&1) ? (u16)(wb>>16) : (u16)wb;
            outw[jj] = (u32)ua | ((u32)ub<<16);
        }
        *(uint4*)(d + (size_t)(p0+pp)*CCH + c0 + cg*8) = make_uint4(outw[0],outw[1],outw[2],outw[3]);
    }
}

// ---------------- NT MFMA GEMM: C[m][n] = sum_k A[m][k]*B[n][k]  (ld=384, K=384) ----------------
// 128x128 tile, BK=64, 4 waves (each 64x64 = 4x4 frags of 16x16), global_load_lds staging,
// XOR-swizzled LDS (linear dest + pre-swizzled source + swizzled read).
// EPI 0: +bias, store bf16 (row-stride HW). EPI 1: +bias +xn(bf16), store f32.
template<int EPI>
__global__ __launch_bounds__(256) void gemm_nt(
    const u16* __restrict__ A, const u16* __restrict__ Bm, void* __restrict__ Cout,
    const float* __restrict__ bias, const u16* __restrict__ xnadd,
    long A_bstride, long B_bstride, long C_bstride)
{
    __shared__ u16 smA[128*64];
    __shared__ u16 smB[128*64];
    int b  = blockIdx.z;
    int n0 = blockIdx.x*128, m0 = blockIdx.y*128;
    const u16* Ab = A  + (size_t)b*A_bstride;
    const u16* Bb = Bm + (size_t)b*B_bstride;
    int t = threadIdx.x;
    int lane = t & 63, w = t >> 6;
    int wr = w >> 1, wc = w & 1;
    int l15 = lane & 15, g = lane >> 4;
    int s7 = l15 & 7;

    f32x4 acc[4][4];
    #pragma unroll
    for (int i=0;i<4;++i)
        #pragma unroll
        for (int j=0;j<4;++j) acc[i][j] = zero4();

    for (int ks = 0; ks < 6; ++ks) {
        int k0 = ks*64;
        #pragma unroll
        for (int r = 0; r < 4; ++r) {
            int e   = (r*256 + t)*8;
            int row = e >> 6, kk = e & 63;
            int kks = kk ^ ((row&7)<<3);      // pre-swizzle source so linear LDS dest is swizzled
            GL16(Ab + (size_t)(m0+row)*CCH + k0 + kks, smA + r*2048 + w*512);
            GL16(Bb + (size_t)(n0+row)*CCH + k0 + kks, smB + r*2048 + w*512);
        }
        __syncthreads();
        #pragma unroll
        for (int kh = 0; kh < 2; ++kh) {
            bf16x8 af[4], bq[4];
            #pragma unroll
            for (int mi=0;mi<4;++mi) {
                int row = wr*64 + mi*16 + l15;
                int u = (kh*4 + g) ^ s7;
                af[mi] = *(const bf16x8*)&smA[row*64 + u*8];
            }
            #pragma unroll
            for (int nj=0;nj<4;++nj) {
                int row = wc*64 + nj*16 + l15;
                int u = (kh*4 + g) ^ s7;
                bq[nj] = *(const bf16x8*)&smB[row*64 + u*8];
            }
            #pragma unroll
            for (int mi=0;mi<4;++mi)
                #pragma unroll
                for (int nj=0;nj<4;++nj)
                    acc[mi][nj] = __builtin_amdgcn_mfma_f32_16x16x32_bf16(af[mi], bq[nj], acc[mi][nj], 0,0,0);
        }
        __syncthreads();
    }
    #pragma unroll
    for (int mi=0;mi<4;++mi) {
        #pragma unroll
        for (int r=0;r<4;++r) {
            int grow = m0 + wr*64 + mi*16 + g*4 + r;
            float bv = bias[grow];
            #pragma unroll
            for (int nj=0;nj<4;++nj) {
                int gcol = n0 + wc*64 + nj*16 + l15;
                float v = acc[mi][nj][r] + bv;
                if (EPI == 0) {
                    ((u16*)Cout)[(size_t)b*C_bstride + (size_t)grow*HW + gcol] = f2bf(v);
                } else {
                    v += bf2f(xnadd[(size_t)b*CCH*HW + (size_t)grow*HW + gcol]);
                    ((float*)Cout)[(size_t)b*C_bstride + (size_t)grow*HW + gcol] = v;
                }
            }
        }
    }
}

// ---------------- depthwise 3x3 SAME, bf16 in/out, [b][c][p] ----------------
__global__ void dw_kernel(const u16* __restrict__ in, u16* __restrict__ out,
                          const float* __restrict__ wd, const float* __restrict__ bd)
{
    int b  = blockIdx.z;
    int c  = blockIdx.y;
    int yt = blockIdx.x;
    int t  = threadIdx.x;
    int ty = t >> 4, tx = t & 15;
    int y  = yt*16 + ty;
    int x0 = tx*8;
    const u16* ib = in + (size_t)b*CCH*HW + (size_t)c*HW;
    float w9[9];
    #pragma unroll
    for (int i=0;i<9;++i) w9[i] = wd[c*9+i];
    float bv = bd[c];
    float rows[3][10];
    #pragma unroll
    for (int dy=0; dy<3; ++dy) {
        int yy = y + dy - 1;
        if (yy < 0 || yy >= WD) { for (int i=0;i<10;++i) rows[dy][i]=0.f; continue; }
        const u16* rp = ib + yy*WD;
        rows[dy][0] = (x0==0) ? 0.f : bf2f(rp[x0-1]);
        uint4 v = *(const uint4*)(rp + x0);
        u16 e[8]; __builtin_memcpy(e,&v,16);
        #pragma unroll
        for (int i=0;i<8;++i) rows[dy][1+i] = bf2f(e[i]);
        rows[dy][9] = (x0+8 >= WD) ? 0.f : bf2f(rp[x0+8]);
    }
    u16 ovals[8];
    #pragma unroll
    for (int xo=0; xo<8; ++xo) {
        float a = bv;
        #pragma unroll
        for (int dy=0;dy<3;++dy)
            #pragma unroll
            for (int dx=0;dx<3;++dx)
                a += rows[dy][xo+dx] * w9[dy*3+dx];
        ovals[xo] = f2bf(a);
    }
    uint4 ov; __builtin_memcpy(&ov, ovals, 16);
    *(uint4*)(out + (size_t)b*CCH*HW + (size_t)c*HW + y*WD + x0) = ov;
}

// ---------------- scores partials: S[i][j] += sum_p K[i,p]*Q[j,p] over a 2048-pixel chunk ----------------
__global__ void scores_kernel(const u16* __restrict__ dwK, const u16* __restrict__ dwQ,
                              float* __restrict__ S_part)
{
    int pc = blockIdx.x;                      // 0..NCHUNK-1 pixel chunks of HW/NCHUNK
    int h  = blockIdx.y;
    int b  = blockIdx.z;
    int lane = threadIdx.x;                   // 64
    int l15 = lane & 15, g = lane >> 4;
    const u16* Kb = dwK + (size_t)b*CCH*HW + (size_t)(h*DH)*HW;
    const u16* Qb = dwQ + (size_t)b*CCH*HW + (size_t)(h*DH)*HW;
    int p0 = pc*(HW/NCHUNK);
    f32x4 acc[3][3];
    #pragma unroll
    for (int i=0;i<3;++i)
        #pragma unroll
        for (int j=0;j<3;++j) acc[i][j] = zero4();
    for (int kk=0; kk<(HW/NCHUNK)/32; ++kk) {
        int p = p0 + kk*32 + g*8;
        bf16x8 af[3], bq[3];
        #pragma unroll
        for (int it=0; it<3; ++it)
            af[it] = *(const bf16x8*)(Kb + (size_t)(it*16 + l15)*HW + p);
        #pragma unroll
        for (int jt=0; jt<3; ++jt)
            bq[jt] = *(const bf16x8*)(Qb + (size_t)(jt*16 + l15)*HW + p);
        #pragma unroll
        for (int it=0;it<3;++it)
            #pragma unroll
            for (int jt=0;jt<3;++jt)
                acc[it][jt] = __builtin_amdgcn_mfma_f32_16x16x32_bf16(af[it], bq[jt], acc[it][jt], 0,0,0);
    }
    float* Sp = S_part + ((size_t)pc*32 + b*NHEAD + h)*(DH*DH);
    #pragma unroll
    for (int it=0;it<3;++it)
        #pragma unroll
        for (int jt=0;jt<3;++jt)
            #pragma unroll
            for (int r=0;r<4;++r) {
                int i = it*16 + g*4 + r;
                int j = jt*16 + l15;
                Sp[i*DH + j] = acc[it][jt][r];
            }
}

// ---------------- reduce partials + softmax over j (256 threads, coalesced reduce) ----------------
__global__ void sm_kernel(const float* __restrict__ S_part, const float* __restrict__ alpha,
                          float* __restrict__ soft)
{
    __shared__ float S[DH*DH];
    int bh = blockIdx.x;                      // b*8+h
    int h  = bh & 7;
    int t  = threadIdx.x;                     // 256
    float ia = 1.f / alpha[h];
    for (int e = t; e < DH*DH; e += 256) {
        float s = 0.f;
        #pragma unroll
        for (int pc=0; pc<NCHUNK; ++pc) s += S_part[((size_t)pc*32 + bh)*(DH*DH) + e];
        S[e] = s * ia;
    }
    __syncthreads();
    if (t < DH) {
        float m = -1e30f;
        for (int j=0;j<DH;++j) m = fmaxf(m, S[t*DH+j]);
        float sum = 0.f;
        for (int j=0;j<DH;++j) sum += __expf(S[t*DH+j]-m);
        float inv = 1.f/sum;
        for (int j=0;j<DH;++j)
            soft[(size_t)bh*(DH*DH) + t*DH + j] = __expf(S[t*DH+j]-m)*inv;
    }
}

// ---------------- fold softmax into wf: wf_eff[b][o][n*48+i] = sum_j wf[o][n*48+j]*soft[b,n,i,j] ----------------
__global__ void fold_kernel(const float* __restrict__ wf, const float* __restrict__ soft,
                            u16* __restrict__ wf_eff)
{
    int idx = blockIdx.x*256 + threadIdx.x;
    if (idx >= NB*CCH*CCH) return;
    int b = idx / (CCH*CCH);
    int rem = idx % (CCH*CCH);
    int o = rem / CCH, c = rem % CCH;
    int n = c / DH, i = c % DH;
    const float* wrow = wf + (size_t)o*CCH + n*DH;
    const float* srow = soft + ((size_t)(b*NHEAD+n))*(DH*DH) + i*DH;
    float a = 0.f;
    #pragma unroll
    for (int j=0;j<DH;++j) a += wrow[j]*srow[j];
    wf_eff[idx] = f2bf(a);
}

extern "C" void kernel_launch(void* const* d_in, const int* in_sizes, int n_in,
                              void* d_out, int out_size, void* d_ws, size_t ws_size,
                              hipStream_t stream)
{
    const float* x    = (const float*)d_in[0];
    const float* ln_g = (const float*)d_in[1];
    const float* ln_b = (const float*)d_in[2];
    const float* wq_p = (const float*)d_in[3];
    const float* bq_p = (const float*)d_in[4];
    const float* wq_d = (const float*)d_in[5];
    const float* bq_d = (const float*)d_in[6];
    const float* wk_p = (const float*)d_in[7];
    const float* bk_p = (const float*)d_in[8];
    const float* wk_d = (const float*)d_in[9];
    const float* bk_d = (const float*)d_in[10];
    const float* wv_p = (const float*)d_in[11];
    const float* bv_p = (const float*)d_in[12];
    const float* wv_d = (const float*)d_in[13];
    const float* bv_d = (const float*)d_in[14];
    const float* alpha= (const float*)d_in[15];
    const float* wf   = (const float*)d_in[16];
    const float* bf_  = (const float*)d_in[17];

    char* ws = (char*)d_ws;
    size_t off = 0;
    auto alloc = [&](size_t bytes)->char* { char* p = ws + off; off += (bytes + 255) & ~(size_t)255; return p; };
    const size_t BIG = (size_t)NB*CCH*HW*2;   // 50.3 MB bf16 [b][384][16384]
    u16* xn_cp = (u16*)alloc(BIG);
    u16* xn_t  = (u16*)alloc(BIG);
    u16* pwA   = (u16*)alloc(BIG);
    u16* dwQ   = (u16*)alloc(BIG);
    u16* dwK   = (u16*)alloc(BIG);
    u16*   Wqkv   = (u16*)  alloc((size_t)3*CCH*CCH*2);
    float* bias_p = (float*)alloc((size_t)3*CCH*4);
    float* wdc    = (float*)alloc((size_t)3*CCH*9*4);
    float* bdc    = (float*)alloc((size_t)3*CCH*4);
    float* S_part = (float*)alloc((size_t)NCHUNK*32*DH*DH*4);
    float* soft   = (float*)alloc((size_t)32*DH*DH*4);
    u16*   wf_eff = (u16*)  alloc((size_t)NB*CCH*CCH*2);
    if (off > ws_size) return;                // insufficient workspace -> leave poison (visible failure)
    u16* V_t = xn_t;                          // xn_t dead after last pointwise GEMM
    u16* dwV = dwQ;                           // dwQ dead after scores

    const long BStr = (long)CCH*HW;

    prep_kernel<<<1778, 256, 0, stream>>>(wq_p,wk_p,wv_p, bq_p,bk_p,bv_p,
                                          wq_d,wk_d,wv_d, bq_d,bk_d,bv_d,
                                          Wqkv, bias_p, wdc, bdc);
    ln_kernel<<<dim3(256,NB), 256, 0, stream>>>(x, ln_g, ln_b, xn_cp);
    transpose_kernel<<<dim3(256,6,NB), 256, 0, stream>>>(xn_cp, xn_t);

    // Q
    gemm_nt<0><<<dim3(128,3,NB), 256, 0, stream>>>(Wqkv,            xn_t, pwA, bias_p,        nullptr, 0, BStr, BStr);
    dw_kernel<<<dim3(8,CCH,NB), 256, 0, stream>>>(pwA, dwQ, wdc,          bdc);
    // K
    gemm_nt<0><<<dim3(128,3,NB), 256, 0, stream>>>(Wqkv + CCH*CCH,  xn_t, pwA, bias_p + CCH,  nullptr, 0, BStr, BStr);
    dw_kernel<<<dim3(8,CCH,NB), 256, 0, stream>>>(pwA, dwK, wdc + CCH*9,  bdc + CCH);
    // attention (tiny): scores -> softmax -> fold into wf
    scores_kernel<<<dim3(NCHUNK,NHEAD,NB), 64, 0, stream>>>(dwK, dwQ, S_part);
    sm_kernel<<<32, 256, 0, stream>>>(S_part, alpha, soft);
    fold_kernel<<<2304, 256, 0, stream>>>(wf, soft, wf_eff);
    // V (reuses dwQ buffer; transpose into xn_t region)
    gemm_nt<0><<<dim3(128,3,NB), 256, 0, stream>>>(Wqkv + 2*CCH*CCH, xn_t, pwA, bias_p + 2*CCH, nullptr, 0, BStr, BStr);
    dw_kernel<<<dim3(8,CCH,NB), 256, 0, stream>>>(pwA, dwV, wdc + 2*CCH*9, bdc + 2*CCH);
    transpose_kernel<<<dim3(256,6,NB), 256, 0, stream>>>(dwV, V_t);
    // final: x_cap = wf_eff x V + bf + xn
    gemm_nt<1><<<dim3(128,3,NB), 256, 0, stream>>>(wf_eff, V_t, d_out, bf_, xn_cp,
                                                   (long)CCH*CCH, BStr, BStr);
}

// Round 3
// 385.126 us; speedup vs baseline: 1.2339x; 1.0459x over previous
//
#include <hip/hip_runtime.h>

// MDTA: B=4, C=384, H=W=128, HEADS=8, D=48
#define HW    16384
#define WD    128
#define CCH   384
#define NB    4
#define NHEAD 8
#define DH    48
#define NCHUNK 8   // score partial chunks (pixels per chunk = HW/NCHUNK = 2048)

typedef unsigned short u16;
typedef unsigned int   u32;
typedef __bf16 bf16x8 __attribute__((ext_vector_type(8)));
typedef float  f32x4  __attribute__((ext_vector_type(4)));

__device__ __forceinline__ float bf2f(u16 u){ u32 t=((u32)u)<<16; float f; __builtin_memcpy(&f,&t,4); return f; }
__device__ __forceinline__ u16 f2bf(float f){ u32 x; __builtin_memcpy(&x,&f,4); u32 r=x+0x7fffu+((x>>16)&1u); return (u16)(r>>16); }
__device__ __forceinline__ f32x4 zero4(){ f32x4 z = {0.f,0.f,0.f,0.f}; return z; }

#define GL16(g,l) __builtin_amdgcn_global_load_lds(\
    (const __attribute__((address_space(1))) void*)(g), \
    (__attribute__((address_space(3))) void*)(l), 16, 0, 0)

// ---------------- prep: cast/concat weights ----------------
__global__ void prep_kernel(const float* wq_p, const float* wk_p, const float* wv_p,
                            const float* bq_p, const float* bk_p, const float* bv_p,
                            const float* wq_d, const float* wk_d, const float* wv_d,
                            const float* bq_d, const float* bk_d, const float* bv_d,
                            u16* Wqkv, float* bias_p, float* wdc, float* bdc)
{
    int idx = blockIdx.x*256 + threadIdx.x;
    const int NW = 3*CCH*CCH;                 // 442368
    if (idx < NW) {
        int m = idx / CCH, c = idx % CCH;
        int w = m / CCH, o = m % CCH;
        const float* src = (w==0)? wq_p : (w==1)? wk_p : wv_p;
        Wqkv[idx] = f2bf(src[o*CCH + c]);
    } else if (idx < NW + 3*CCH) {
        int m = idx - NW; int w = m/CCH, o = m%CCH;
        const float* src = (w==0)? bq_p : (w==1)? bk_p : bv_p;
        bias_p[m] = src[o];
    } else if (idx < NW + 3*CCH + 3*CCH*9) {
        int r = idx - NW - 3*CCH; int m = r/9, k = r%9;
        int w = m/CCH, o = m%CCH;
        const float* src = (w==0)? wq_d : (w==1)? wk_d : wv_d;
        wdc[r] = src[o*9 + k];
    } else if (idx < NW + 3*CCH + 3*CCH*9 + 3*CCH) {
        int m = idx - NW - 3*CCH - 3*CCH*9; int w = m/CCH, o = m%CCH;
        const float* src = (w==0)? bq_d : (w==1)? bk_d : bv_d;
        bdc[m] = src[o];
    }
}

// ---------------- LayerNorm over C per pixel -> xn bf16 [b][c][p] ----------------
// 256 threads / 64 pixels per block. tx = pixel quad (float4), cg = channel group of 24.
// Raw values kept in registers (vals[24]) -> single global pass.
__global__ __launch_bounds__(256) void ln_kernel(
    const float* __restrict__ x, const float* __restrict__ gamma,
    const float* __restrict__ beta, u16* __restrict__ xn)
{
    __shared__ f32x4 redS[16][16];
    __shared__ f32x4 redS2[16][16];
    __shared__ float mu_s[64], rs_s[64];
    int b  = blockIdx.y;
    int p0 = blockIdx.x*64;
    int t  = threadIdx.x;
    int tx = t & 15, cg = t >> 4;
    const float* xb = x + (size_t)b*CCH*HW + p0 + tx*4;
    f32x4 vals[24];
    f32x4 s = zero4(), s2 = zero4();
    #pragma unroll
    for (int cc = 0; cc < 24; ++cc) {
        int c = cg*24 + cc;
        f32x4 v = *(const f32x4*)(xb + (size_t)c*HW);
        vals[cc] = v;
        s += v; s2 += v*v;
    }
    redS[cg][tx] = s; redS2[cg][tx] = s2;
    __syncthreads();
    if (t < 64) {
        int q = t >> 2, comp = t & 3;
        const float* rs1 = (const float*)redS;
        const float* rs2 = (const float*)redS2;
        float st = 0.f, st2 = 0.f;
        #pragma unroll
        for (int g2 = 0; g2 < 16; ++g2) {
            st  += rs1[(g2*16+q)*4 + comp];
            st2 += rs2[(g2*16+q)*4 + comp];
        }
        float mu  = st*(1.f/CCH);
        float var = st2*(1.f/CCH) - mu*mu;
        mu_s[t] = mu;
        rs_s[t] = rsqrtf(var + 1e-5f);
    }
    __syncthreads();
    f32x4 mu4, rs4;
    #pragma unroll
    for (int j = 0; j < 4; ++j) { mu4[j] = mu_s[tx*4+j]; rs4[j] = rs_s[tx*4+j]; }
    u16* xo = xn + (size_t)b*CCH*HW + p0 + tx*4;
    #pragma unroll
    for (int cc = 0; cc < 24; ++cc) {
        int c = cg*24 + cc;
        float gm = gamma[c], bt = beta[c];
        f32x4 v = (vals[cc] - mu4) * rs4;
        u16 o0 = f2bf(v[0]*gm + bt), o1 = f2bf(v[1]*gm + bt);
        u16 o2 = f2bf(v[2]*gm + bt), o3 = f2bf(v[3]*gm + bt);
        uint2 pk;
        pk.x = (u32)o0 | ((u32)o1 << 16);
        pk.y = (u32)o2 | ((u32)o3 << 16);
        *(uint2*)(xo + (size_t)c*HW) = pk;
    }
}

// ---------------- bf16 transpose per batch: [Cs][16384] slice -> [16384][384] ----------------
__global__ void transpose_kernel(const u16* __restrict__ src, u16* __restrict__ dst,
                                 long src_bstride)
{
    __shared__ u32 tile[64][33];              // u32 = 2 bf16 along p
    int b  = blockIdx.z;
    int p0 = blockIdx.x*64, c0 = blockIdx.y*64;
    const u16* s = src + (size_t)b*src_bstride;
    u16*       d = dst + (size_t)b*CCH*HW;
    int t = threadIdx.x;
    #pragma unroll
    for (int q = 0; q < 2; ++q) {
        int cc = q*32 + (t>>3), pg = t&7;
        uint4 v = *(const uint4*)(s + (size_t)(c0+cc)*HW + p0 + pg*8);
        tile[cc][pg*4+0] = v.x; tile[cc][pg*4+1] = v.y;
        tile[cc][pg*4+2] = v.z; tile[cc][pg*4+3] = v.w;
    }
    __syncthreads();
    #pragma unroll
    for (int q = 0; q < 2; ++q) {
        int pp = q*32 + (t>>3), cg = t&7;
        u32 outw[4];
        #pragma unroll
        for (int jj = 0; jj < 4; ++jj) {
            int c_a = cg*8 + jj*2;
            u32 wa = tile[c_a  ][pp>>1];
            u32 wb = tile[c_a+1][pp>>1];
            u16 ua = (pp&1) ? (u16)(wa>>16) : (u16)wa;
            u16 ub = (pp&1) ? (u16)(wb>>16) : (u16)wb;
            outw[jj] = (u32)ua | ((u32)ub<<16);
        }
        *(uint4*)(d + (size_t)(p0+pp)*CCH + c0 + cg*8) = make_uint4(outw[0],outw[1],outw[2],outw[3]);
    }
}

// ---------------- NT MFMA GEMM: C[m][n] = sum_k A[m][k]*B[n][k]  (ld=384, K=384) ----------------
// 128x128 tile, BK=64, 8 waves (each 64x32 = 4x2 frags) -> 32 AGPR acc, higher occupancy.
// grid: (mTiles, nTiles=128, NB); x = m so consecutive blocks share the B-tile (L2).
// EPI 0: +bias, store bf16 (row-stride HW). EPI 1: +bias +xn(bf16), store f32.
template<int EPI>
__global__ __launch_bounds__(512) void gemm_nt(
    const u16* __restrict__ A, const u16* __restrict__ Bm, void* __restrict__ Cout,
    const float* __restrict__ bias, const u16* __restrict__ xnadd,
    long A_bstride, long B_bstride, long C_bstride)
{
    __shared__ u16 smA[128*64];
    __shared__ u16 smB[128*64];
    int b  = blockIdx.z;
    int m0 = blockIdx.x*128, n0 = blockIdx.y*128;
    const u16* Ab = A  + (size_t)b*A_bstride;
    const u16* Bb = Bm + (size_t)b*B_bstride;
    int t = threadIdx.x;
    int lane = t & 63, w = t >> 6;
    int wr = w >> 2, wc = w & 3;              // rows wr*64.., cols wc*32..
    int l15 = lane & 15, g = lane >> 4;
    int s7 = l15 & 7;

    f32x4 acc[4][2];
    #pragma unroll
    for (int i=0;i<4;++i)
        #pragma unroll
        for (int j=0;j<2;++j) acc[i][j] = zero4();

    for (int ks = 0; ks < 6; ++ks) {
        int k0 = ks*64;
        #pragma unroll
        for (int r = 0; r < 2; ++r) {
            int e   = (r*512 + t)*8;
            int row = e >> 6, kk = e & 63;
            int kks = kk ^ ((row&7)<<3);      // pre-swizzle source so linear LDS dest is swizzled
            GL16(Ab + (size_t)(m0+row)*CCH + k0 + kks, smA + r*4096 + w*512);
            GL16(Bb + (size_t)(n0+row)*CCH + k0 + kks, smB + r*4096 + w*512);
        }
        __syncthreads();
        #pragma unroll
        for (int kh = 0; kh < 2; ++kh) {
            int u = (kh*4 + g) ^ s7;
            bf16x8 af[4], bq[2];
            #pragma unroll
            for (int mi=0;mi<4;++mi) {
                int row = wr*64 + mi*16 + l15;
                af[mi] = *(const bf16x8*)&smA[row*64 + u*8];
            }
            #pragma unroll
            for (int nj=0;nj<2;++nj) {
                int row = wc*32 + nj*16 + l15;
                bq[nj] = *(const bf16x8*)&smB[row*64 + u*8];
            }
            #pragma unroll
            for (int mi=0;mi<4;++mi)
                #pragma unroll
                for (int nj=0;nj<2;++nj)
                    acc[mi][nj] = __builtin_amdgcn_mfma_f32_16x16x32_bf16(af[mi], bq[nj], acc[mi][nj], 0,0,0);
        }
        __syncthreads();
    }
    #pragma unroll
    for (int mi=0;mi<4;++mi) {
        #pragma unroll
        for (int r=0;r<4;++r) {
            int grow = m0 + wr*64 + mi*16 + g*4 + r;
            float bv = bias[grow];
            #pragma unroll
            for (int nj=0;nj<2;++nj) {
                int gcol = n0 + wc*32 + nj*16 + l15;
                float v = acc[mi][nj][r] + bv;
                if (EPI == 0) {
                    ((u16*)Cout)[(size_t)b*C_bstride + (size_t)grow*HW + gcol] = f2bf(v);
                } else {
                    v += bf2f(xnadd[(size_t)b*CCH*HW + (size_t)grow*HW + gcol]);
                    ((float*)Cout)[(size_t)b*C_bstride + (size_t)grow*HW + gcol] = v;
                }
            }
        }
    }
}

// ---------------- depthwise 3x3 SAME, bf16 in/out, [b][cpb][p] ----------------
__global__ void dw_kernel(const u16* __restrict__ in, u16* __restrict__ out,
                          const float* __restrict__ wd, const float* __restrict__ bd,
                          int cpb)
{
    int b  = blockIdx.z;
    int c  = blockIdx.y;
    int yt = blockIdx.x;
    int t  = threadIdx.x;
    int ty = t >> 4, tx = t & 15;
    int y  = yt*16 + ty;
    int x0 = tx*8;
    const u16* ib = in + (size_t)b*cpb*HW + (size_t)c*HW;
    float w9[9];
    #pragma unroll
    for (int i=0;i<9;++i) w9[i] = wd[c*9+i];
    float bv = bd[c];
    float rows[3][10];
    #pragma unroll
    for (int dy=0; dy<3; ++dy) {
        int yy = y + dy - 1;
        if (yy < 0 || yy >= WD) { for (int i=0;i<10;++i) rows[dy][i]=0.f; continue; }
        const u16* rp = ib + yy*WD;
        rows[dy][0] = (x0==0) ? 0.f : bf2f(rp[x0-1]);
        uint4 v = *(const uint4*)(rp + x0);
        u16 e[8]; __builtin_memcpy(e,&v,16);
        #pragma unroll
        for (int i=0;i<8;++i) rows[dy][1+i] = bf2f(e[i]);
        rows[dy][9] = (x0+8 >= WD) ? 0.f : bf2f(rp[x0+8]);
    }
    u16 ovals[8];
    #pragma unroll
    for (int xo=0; xo<8; ++xo) {
        float a = bv;
        #pragma unroll
        for (int dy=0;dy<3;++dy)
            #pragma unroll
            for (int dx=0;dx<3;++dx)
                a += rows[dy][xo+dx] * w9[dy*3+dx];
        ovals[xo] = f2bf(a);
    }
    uint4 ov; __builtin_memcpy(&ov, ovals, 16);
    *(uint4*)(out + (size_t)b*cpb*HW + (size_t)c*HW + y*WD + x0) = ov;
}

// ---------------- scores partials: S[i][j] += sum_p K[i,p]*Q[j,p] over a 2048-pixel chunk ----------------
__global__ void scores_kernel(const u16* __restrict__ Kp, const u16* __restrict__ Qp,
                              float* __restrict__ S_part, int cpb)
{
    int pc = blockIdx.x;                      // 0..NCHUNK-1 pixel chunks
    int h  = blockIdx.y;
    int b  = blockIdx.z;
    int lane = threadIdx.x;                   // 64
    int l15 = lane & 15, g = lane >> 4;
    const u16* Kb = Kp + (size_t)b*cpb*HW + (size_t)(h*DH)*HW;
    const u16* Qb = Qp + (size_t)b*cpb*HW + (size_t)(h*DH)*HW;
    int p0 = pc*(HW/NCHUNK);
    f32x4 acc[3][3];
    #pragma unroll
    for (int i=0;i<3;++i)
        #pragma unroll
        for (int j=0;j<3;++j) acc[i][j] = zero4();
    for (int kk=0; kk<(HW/NCHUNK)/32; ++kk) {
        int p = p0 + kk*32 + g*8;
        bf16x8 af[3], bq[3];
        #pragma unroll
        for (int it=0; it<3; ++it)
            af[it] = *(const bf16x8*)(Kb + (size_t)(it*16 + l15)*HW + p);
        #pragma unroll
        for (int jt=0; jt<3; ++jt)
            bq[jt] = *(const bf16x8*)(Qb + (size_t)(jt*16 + l15)*HW + p);
        #pragma unroll
        for (int it=0;it<3;++it)
            #pragma unroll
            for (int jt=0;jt<3;++jt)
                acc[it][jt] = __builtin_amdgcn_mfma_f32_16x16x32_bf16(af[it], bq[jt], acc[it][jt], 0,0,0);
    }
    float* Sp = S_part + ((size_t)pc*32 + b*NHEAD + h)*(DH*DH);
    #pragma unroll
    for (int it=0;it<3;++it)
        #pragma unroll
        for (int jt=0;jt<3;++jt)
            #pragma unroll
            for (int r=0;r<4;++r) {
                int i = it*16 + g*4 + r;
                int j = jt*16 + l15;
                Sp[i*DH + j] = acc[it][jt][r];
            }
}

// ---------------- reduce partials + softmax over j (256 threads, coalesced reduce) ----------------
__global__ void sm_kernel(const float* __restrict__ S_part, const float* __restrict__ alpha,
                          float* __restrict__ soft)
{
    __shared__ float S[DH*DH];
    int bh = blockIdx.x;                      // b*8+h
    int h  = bh & 7;
    int t  = threadIdx.x;                     // 256
    float ia = 1.f / alpha[h];
    for (int e = t; e < DH*DH; e += 256) {
        float s = 0.f;
        #pragma unroll
        for (int pc=0; pc<NCHUNK; ++pc) s += S_part[((size_t)pc*32 + bh)*(DH*DH) + e];
        S[e] = s * ia;
    }
    __syncthreads();
    if (t < DH) {
        float m = -1e30f;
        for (int j=0;j<DH;++j) m = fmaxf(m, S[t*DH+j]);
        float sum = 0.f;
        for (int j=0;j<DH;++j) sum += __expf(S[t*DH+j]-m);
        float inv = 1.f/sum;
        for (int j=0;j<DH;++j)
            soft[(size_t)bh*(DH*DH) + t*DH + j] = __expf(S[t*DH+j]-m)*inv;
    }
}

// ---------------- fold softmax into wf: wf_eff[b][o][n*48+i] = sum_j wf[o][n*48+j]*soft[b,n,i,j] ----------------
__global__ void fold_kernel(const float* __restrict__ wf, const float* __restrict__ soft,
                            u16* __restrict__ wf_eff)
{
    int idx = blockIdx.x*256 + threadIdx.x;
    if (idx >= NB*CCH*CCH) return;
    int b = idx / (CCH*CCH);
    int rem = idx % (CCH*CCH);
    int o = rem / CCH, c = rem % CCH;
    int n = c / DH, i = c % DH;
    const float* wrow = wf + (size_t)o*CCH + n*DH;
    const float* srow = soft + ((size_t)(b*NHEAD+n))*(DH*DH) + i*DH;
    float a = 0.f;
    #pragma unroll
    for (int j=0;j<DH;++j) a += wrow[j]*srow[j];
    wf_eff[idx] = f2bf(a);
}

extern "C" void kernel_launch(void* const* d_in, const int* in_sizes, int n_in,
                              void* d_out, int out_size, void* d_ws, size_t ws_size,
                              hipStream_t stream)
{
    const float* x    = (const float*)d_in[0];
    const float* ln_g = (const float*)d_in[1];
    const float* ln_b = (const float*)d_in[2];
    const float* wq_p = (const float*)d_in[3];
    const float* bq_p = (const float*)d_in[4];
    const float* wq_d = (const float*)d_in[5];
    const float* bq_d = (const float*)d_in[6];
    const float* wk_p = (const float*)d_in[7];
    const float* bk_p = (const float*)d_in[8];
    const float* wk_d = (const float*)d_in[9];
    const float* bk_d = (const float*)d_in[10];
    const float* wv_p = (const float*)d_in[11];
    const float* bv_p = (const float*)d_in[12];
    const float* wv_d = (const float*)d_in[13];
    const float* bv_d = (const float*)d_in[14];
    const float* alpha= (const float*)d_in[15];
    const float* wf   = (const float*)d_in[16];
    const float* bf_  = (const float*)d_in[17];

    char* ws = (char*)d_ws;
    size_t off = 0;
    auto alloc = [&](size_t bytes)->char* { char* p = ws + off; off += (bytes + 255) & ~(size_t)255; return p; };
    const size_t BIG  = (size_t)NB*CCH*HW*2;       // 50.3 MB bf16 [b][384][16384]
    const size_t BIG3 = 3*BIG;                     // 151 MB   [b][1152][16384]
    const size_t SMALLS = (size_t)3*CCH*CCH*2 + 3*CCH*4 + 3*CCH*9*4 + 3*CCH*4
                        + (size_t)NCHUNK*32*DH*DH*4 + (size_t)32*DH*DH*4
                        + (size_t)NB*CCH*CCH*2 + 16*256;
    const size_t NEED_FUSED = 2*BIG + 2*BIG3 + SMALLS;
    const bool fused = (ws_size >= NEED_FUSED);
    const long BStr = (long)CCH*HW;

    if (fused) {
        u16* xn_cp  = (u16*)alloc(BIG);
        u16* xn_t   = (u16*)alloc(BIG);
        u16* pwQKV  = (u16*)alloc(BIG3);
        u16* dwQKV  = (u16*)alloc(BIG3);
        u16*   Wqkv   = (u16*)  alloc((size_t)3*CCH*CCH*2);
        float* bias_p = (float*)alloc((size_t)3*CCH*4);
        float* wdc    = (float*)alloc((size_t)3*CCH*9*4);
        float* bdc    = (float*)alloc((size_t)3*CCH*4);
        float* S_part = (float*)alloc((size_t)NCHUNK*32*DH*DH*4);
        float* soft   = (float*)alloc((size_t)32*DH*DH*4);
        u16*   wf_eff = (u16*)  alloc((size_t)NB*CCH*CCH*2);
        u16* V_t = xn_t;                       // xn_t dead after the fused gemm

        prep_kernel<<<1778, 256, 0, stream>>>(wq_p,wk_p,wv_p, bq_p,bk_p,bv_p,
                                              wq_d,wk_d,wv_d, bq_d,bk_d,bv_d,
                                              Wqkv, bias_p, wdc, bdc);
        ln_kernel<<<dim3(256,NB), 256, 0, stream>>>(x, ln_g, ln_b, xn_cp);
        transpose_kernel<<<dim3(256,6,NB), 256, 0, stream>>>(xn_cp, xn_t, BStr);
        // fused QKV pointwise: M=1152
        gemm_nt<0><<<dim3(9,128,NB), 512, 0, stream>>>(Wqkv, xn_t, pwQKV, bias_p, nullptr,
                                                       0, BStr, (long)3*CCH*HW);
        dw_kernel<<<dim3(8,3*CCH,NB), 256, 0, stream>>>(pwQKV, dwQKV, wdc, bdc, 3*CCH);
        scores_kernel<<<dim3(NCHUNK,NHEAD,NB), 64, 0, stream>>>(dwQKV + (size_t)CCH*HW,  // K
                                                                dwQKV,                   // Q
                                                                S_part, 3*CCH);
        sm_kernel<<<32, 256, 0, stream>>>(S_part, alpha, soft);
        fold_kernel<<<2304, 256, 0, stream>>>(wf, soft, wf_eff);
        transpose_kernel<<<dim3(256,6,NB), 256, 0, stream>>>(dwQKV + (size_t)2*CCH*HW, V_t,
                                                             (long)3*CCH*HW);
        gemm_nt<1><<<dim3(3,128,NB), 512, 0, stream>>>(wf_eff, V_t, d_out, bf_, xn_cp,
                                                       (long)CCH*CCH, BStr, BStr);
    } else {
        u16* xn_cp = (u16*)alloc(BIG);
        u16* xn_t  = (u16*)alloc(BIG);
        u16* pwA   = (u16*)alloc(BIG);
        u16* dwQ   = (u16*)alloc(BIG);
        u16* dwK   = (u16*)alloc(BIG);
        u16*   Wqkv   = (u16*)  alloc((size_t)3*CCH*CCH*2);
        float* bias_p = (float*)alloc((size_t)3*CCH*4);
        float* wdc    = (float*)alloc((size_t)3*CCH*9*4);
        float* bdc    = (float*)alloc((size_t)3*CCH*4);
        float* S_part = (float*)alloc((size_t)NCHUNK*32*DH*DH*4);
        float* soft   = (float*)alloc((size_t)32*DH*DH*4);
        u16*   wf_eff = (u16*)  alloc((size_t)NB*CCH*CCH*2);
        if (off > ws_size) return;
        u16* V_t = xn_t;
        u16* dwV = dwQ;

        prep_kernel<<<1778, 256, 0, stream>>>(wq_p,wk_p,wv_p, bq_p,bk_p,bv_p,
                                              wq_d,wk_d,wv_d, bq_d,bk_d,bv_d,
                                              Wqkv, bias_p, wdc, bdc);
        ln_kernel<<<dim3(256,NB), 256, 0, stream>>>(x, ln_g, ln_b, xn_cp);
        transpose_kernel<<<dim3(256,6,NB), 256, 0, stream>>>(xn_cp, xn_t, BStr);
        gemm_nt<0><<<dim3(3,128,NB), 512, 0, stream>>>(Wqkv,           xn_t, pwA, bias_p,       nullptr, 0, BStr, BStr);
        dw_kernel<<<dim3(8,CCH,NB), 256, 0, stream>>>(pwA, dwQ, wdc,         bdc,       CCH);
        gemm_nt<0><<<dim3(3,128,NB), 512, 0, stream>>>(Wqkv + CCH*CCH, xn_t, pwA, bias_p + CCH, nullptr, 0, BStr, BStr);
        dw_kernel<<<dim3(8,CCH,NB), 256, 0, stream>>>(pwA, dwK, wdc + CCH*9, bdc + CCH, CCH);
        scores_kernel<<<dim3(NCHUNK,NHEAD,NB), 64, 0, stream>>>(dwK, dwQ, S_part, CCH);
        sm_kernel<<<32, 256, 0, stream>>>(S_part, alpha, soft);
        fold_kernel<<<2304, 256, 0, stream>>>(wf, soft, wf_eff);
        gemm_nt<0><<<dim3(3,128,NB), 512, 0, stream>>>(Wqkv + 2*CCH*CCH, xn_t, pwA, bias_p + 2*CCH, nullptr, 0, BStr, BStr);
        dw_kernel<<<dim3(8,CCH,NB), 256, 0, stream>>>(pwA, dwV, wdc + 2*CCH*9, bdc + 2*CCH, CCH);
        transpose_kernel<<<dim3(256,6,NB), 256, 0, stream>>>(dwV, V_t, BStr);
        gemm_nt<1><<<dim3(3,128,NB), 512, 0, stream>>>(wf_eff, V_t, d_out, bf_, xn_cp,
                                                       (long)CCH*CCH, BStr, BStr);
    }
}